// Round 4
// baseline (7497.560 us; speedup 1.0000x reference)
//
#include <hip/hip_runtime.h>
#include <stdint.h>

// Problem constants
constexpr int T_STEPS = 512;
constexpr int BSZ     = 256;
constexpr int OBSD    = 64;
constexpr int HID     = 512;
constexpr int NROWS   = T_STEPS * BSZ;   // 131072

// LSTM partitioning: 8 groups x 32 WGs; group owns 32 batch rows; WG owns 16 h-cols
constexpr int GROUPS = 8;
constexpr int WPG    = 32;
constexpr int BW     = 32;

typedef __attribute__((ext_vector_type(8))) short bf16x8;
typedef __attribute__((ext_vector_type(4))) float f32x4;

__device__ __forceinline__ float bf2f(uint16_t u) {
  union { uint32_t i; float f; } v; v.i = ((uint32_t)u) << 16; return v.f;
}
__device__ __forceinline__ uint16_t f2bf(float f) {
  union { float f; uint32_t i; } v; v.f = f;
  return (uint16_t)((v.i + 0x7FFFu + ((v.i >> 16) & 1u)) >> 16);
}
__device__ __forceinline__ uint64_t pack4(float a, float b, float c, float d) {
  uint32_t lo = (uint32_t)f2bf(a) | ((uint32_t)f2bf(b) << 16);
  uint32_t hi = (uint32_t)f2bf(c) | ((uint32_t)f2bf(d) << 16);
  return (uint64_t)lo | ((uint64_t)hi << 32);
}
__device__ __forceinline__ float sigm(float x) { return 1.f / (1.f + __expf(-x)); }
__device__ __forceinline__ float tanh_fast(float x) {
  float e = __expf(2.f * x);
  return 1.f - 2.f / (e + 1.f);
}

__device__ __forceinline__ void gll16(const void* g, void* l) {
  __builtin_amdgcn_global_load_lds(
      (const __attribute__((address_space(1))) uint32_t*)g,
      (__attribute__((address_space(3))) uint32_t*)l, 16, 0, 0);
}

// ---------------------------------------------------------------------------
// Persistent LSTM scan kernel. 256 blocks x 256 threads, 1 block/CU.
// - Weights live in VGPRs (18 x bf16x8 per wave) -- zero ds_reads for B operand.
// - h exchange: coalesced agent-scope u64 loads (each instr = contiguous 512B).
// - Sync: versioned per-WG flags; all 4 waves poll independently (busy, no
//   sleep), one agent-acquire fence per wave per step.
// - done/x loads hoisted above the poll so their latency overlaps detection.
// LDS: Ab 36864 B | gl 8704 B (pad 17) | bl 256 B  = 45824 B (static)
// ---------------------------------------------------------------------------
__global__ __launch_bounds__(256, 1) void lstm_kernel(
    const float* __restrict__ xin, const float* __restrict__ done,
    const float* __restrict__ h0, const float* __restrict__ c0,
    const float* __restrict__ W_ih, const float* __restrict__ W_hh,
    const float* __restrict__ b_ih, const float* __restrict__ b_hh,
    uint16_t* __restrict__ hs, uint32_t* __restrict__ flg,
    float* __restrict__ out)
{
  __shared__ char  Ab[32 * 1152];
  __shared__ float gl[4 * 544];     // [gate][32 rows][17 pad]
  __shared__ float bl[64];

  const int wg   = blockIdx.x;
  const int g    = wg / WPG;
  const int win  = wg % WPG;
  const int bg   = g * BW;
  const int tid  = threadIdx.x;
  const int lane = tid & 63;
  const int q    = tid >> 6;   // wave id == gate id (i,f,g,o)

  // ---- one-time: this wave's weight fragments straight into VGPRs ----
  bf16x8 bq[18];
  {
    const int wrow = q * 512 + win * 16 + (lane & 15);
    const int kg8  = (lane >> 4) * 8;
    #pragma unroll
    for (int ks = 0; ks < 18; ++ks) {
      const float* src = (ks < 16)
          ? (W_hh + (size_t)wrow * 512 + ks * 32 + kg8)
          : (W_ih + (size_t)wrow * 64 + (ks - 16) * 32 + kg8);
      float4 a = *(const float4*)src;
      float4 b = *(const float4*)(src + 4);
      bf16x8 v;
      v[0] = (short)f2bf(a.x); v[1] = (short)f2bf(a.y);
      v[2] = (short)f2bf(a.z); v[3] = (short)f2bf(a.w);
      v[4] = (short)f2bf(b.x); v[5] = (short)f2bf(b.y);
      v[6] = (short)f2bf(b.z); v[7] = (short)f2bf(b.w);
      bq[ks] = v;
    }
  }
  if (tid < 64) {
    int q2 = tid >> 4, c = tid & 15;
    int grow = q2 * 512 + win * 16 + c;
    bl[tid] = b_ih[grow] + b_hh[grow];
  }

  const int b_loc = tid >> 3;        // 0..31 (batch row within group)
  const int n0    = (tid & 7) * 2;   // h-col pair within WG's 16 cols
  float creg0 = c0[(size_t)(bg + b_loc) * HID + win * 16 + n0];
  float creg1 = c0[(size_t)(bg + b_loc) * HID + win * 16 + n0 + 1];

  const int sr  = tid >> 3;          // x staging row
  const int sc8 = (tid & 7) * 8;     // x col base
  const int rw  = q * 8;             // wave's first h row

  __syncthreads();

  for (int t = 0; t < T_STEPS; ++t) {
    // ---- hoisted loads (overlap the poll): x_t, done values ----
    const float* xp = xin + ((size_t)t * BSZ + bg + sr) * OBSD + sc8;
    float4 xa = *(const float4*)xp;
    float4 xb = *(const float4*)(xp + 4);
    float dvs[8];
    #pragma unroll
    for (int r8 = 0; r8 < 8; ++r8)
      dvs[r8] = done[(size_t)t * BSZ + bg + rw + r8];
    float dv_b = done[(size_t)t * BSZ + bg + b_loc];

    // stage x_t into Ab (after end-of-prev-step barrier -> no race with MFMA)
    {
      uint4 u4;
      u4.x = (uint32_t)f2bf(xa.x) | ((uint32_t)f2bf(xa.y) << 16);
      u4.y = (uint32_t)f2bf(xa.z) | ((uint32_t)f2bf(xa.w) << 16);
      u4.z = (uint32_t)f2bf(xb.x) | ((uint32_t)f2bf(xb.y) << 16);
      u4.w = (uint32_t)f2bf(xb.z) | ((uint32_t)f2bf(xb.w) << 16);
      *(uint4*)(Ab + ((sr * 1152 + 1024 + sc8 * 2) ^ ((sr & 7) << 4))) = u4;
    }

    // ---- wait for the whole group's step t-1 flags (every wave polls) ----
    if (t > 0) {
      for (;;) {
        uint32_t f = (lane < WPG)
            ? __hip_atomic_load(flg + g * 32 + lane, __ATOMIC_RELAXED, __HIP_MEMORY_SCOPE_AGENT)
            : 0xFFFFFFFFu;
        if (__all((int)(f >= (uint32_t)t))) break;
      }
      __builtin_amdgcn_fence(__ATOMIC_ACQUIRE, "agent");
    }

    // ---- stage h_{t-1}: wave loads its 8 rows, coalesced 512B per instr ----
    if (t == 0) {
      #pragma unroll
      for (int r8 = 0; r8 < 8; ++r8) {
        int r = rw + r8;
        uint64_t v0 = 0, v1 = 0;
        if (dvs[r8] <= 0.5f) {
          const float* hp = h0 + (size_t)(bg + r) * HID;
          float4 ha = *(const float4*)(hp + lane * 4);
          float4 hb = *(const float4*)(hp + 256 + lane * 4);
          v0 = pack4(ha.x, ha.y, ha.z, ha.w);
          v1 = pack4(hb.x, hb.y, hb.z, hb.w);
        }
        *(uint64_t*)(Ab + ((r * 1152 + lane * 8) ^ ((r & 7) << 4))) = v0;
        *(uint64_t*)(Ab + ((r * 1152 + 512 + lane * 8) ^ ((r & 7) << 4))) = v1;
      }
    } else {
      #pragma unroll
      for (int r8 = 0; r8 < 8; ++r8) {
        int r = rw + r8;
        const uint64_t* hrow =
            (const uint64_t*)hs + ((size_t)(t - 1) * BSZ + bg + r) * 128;
        uint64_t v0 = __hip_atomic_load(hrow + lane, __ATOMIC_RELAXED, __HIP_MEMORY_SCOPE_AGENT);
        uint64_t v1 = __hip_atomic_load(hrow + 64 + lane, __ATOMIC_RELAXED, __HIP_MEMORY_SCOPE_AGENT);
        if (dvs[r8] > 0.5f) { v0 = 0; v1 = 0; }
        *(uint64_t*)(Ab + ((r * 1152 + lane * 8) ^ ((r & 7) << 4))) = v0;
        *(uint64_t*)(Ab + ((r * 1152 + 512 + lane * 8) ^ ((r & 7) << 4))) = v1;
      }
    }
    __syncthreads();

    // ---- MFMA: gates[32 batch, 16 cols] for wave's gate q (B from VGPRs) ----
    f32x4 ac0 = {0.f, 0.f, 0.f, 0.f};
    f32x4 ac1 = {0.f, 0.f, 0.f, 0.f};
    {
      const int ar = lane & 15;
      const int kg = lane >> 4;
      #pragma unroll
      for (int ks = 0; ks < 18; ++ks) {
        int kb = (ks * 32 + kg * 8) * 2;
        bf16x8 a0 = *(const bf16x8*)(Ab + ((ar * 1152 + kb) ^ ((ar & 7) << 4)));
        bf16x8 a1 = *(const bf16x8*)(Ab + (((ar + 16) * 1152 + kb) ^ ((ar & 7) << 4)));
        ac0 = __builtin_amdgcn_mfma_f32_16x16x32_bf16(a0, bq[ks], ac0, 0, 0, 0);
        ac1 = __builtin_amdgcn_mfma_f32_16x16x32_bf16(a1, bq[ks], ac1, 0, 0, 0);
      }
    }
    // ---- gates -> LDS exchange (rows padded to 17 words) ----
    {
      int c  = lane & 15;
      int rb = (lane >> 4) * 4;
      #pragma unroll
      for (int r = 0; r < 4; ++r) {
        gl[q * 544 + (rb + r) * 17 + c]      = ac0[r];
        gl[q * 544 + (16 + rb + r) * 17 + c] = ac1[r];
      }
    }
    __syncthreads();
    // ---- cell update (c lives in registers across all 512 steps) ----
    {
      float m = dv_b > 0.5f ? 0.f : 1.f;
      float h0v, h1v;
      {
        float I = gl[b_loc * 17 + n0]         + bl[n0];
        float F = gl[544 + b_loc * 17 + n0]   + bl[16 + n0];
        float G = gl[1088 + b_loc * 17 + n0]  + bl[32 + n0];
        float O = gl[1632 + b_loc * 17 + n0]  + bl[48 + n0];
        float cc = creg0 * m;
        cc = sigm(F) * cc + sigm(I) * tanh_fast(G);
        creg0 = cc;
        h0v = sigm(O) * tanh_fast(cc);
      }
      {
        int n1 = n0 + 1;
        float I = gl[b_loc * 17 + n1]         + bl[n1];
        float F = gl[544 + b_loc * 17 + n1]   + bl[16 + n1];
        float G = gl[1088 + b_loc * 17 + n1]  + bl[32 + n1];
        float O = gl[1632 + b_loc * 17 + n1]  + bl[48 + n1];
        float cc = creg1 * m;
        cc = sigm(F) * cc + sigm(I) * tanh_fast(G);
        creg1 = cc;
        h1v = sigm(O) * tanh_fast(cc);
      }
      uint32_t pk = (uint32_t)f2bf(h0v) | ((uint32_t)f2bf(h1v) << 16);
      uint32_t* hp = (uint32_t*)(hs + ((size_t)t * BSZ + bg + b_loc) * HID + win * 16 + n0);
      __hip_atomic_store(hp, pk, __ATOMIC_RELAXED, __HIP_MEMORY_SCOPE_AGENT);
      if (t == T_STEPS - 1) {
        size_t ob = (size_t)(bg + b_loc) * HID + win * 16 + n0;
        out[NROWS + ob]         = h0v;
        out[NROWS + ob + 1]     = h1v;
        out[2 * NROWS + ob]     = creg0;
        out[2 * NROWS + ob + 1] = creg1;
      }
    }
    __syncthreads();   // per-wave vmcnt(0) drain before barrier -> h visible
    if (tid == 0)
      __hip_atomic_store(flg + g * 32 + win, (uint32_t)(t + 1),
                         __ATOMIC_RELEASE, __HIP_MEMORY_SCOPE_AGENT);
  }
}

// ---------------------------------------------------------------------------
// Per-row LayerNorm stats from bf16 hidden: rstd[m], murs[m] = mu*rstd.
// One wave per row.
// ---------------------------------------------------------------------------
__global__ void ln_stats_kernel(const uint16_t* __restrict__ hsrc,
                                float* __restrict__ rstd_a, float* __restrict__ murs_a)
{
  const int lane = threadIdx.x & 63;
  const size_t row = (size_t)blockIdx.x * 4 + (threadIdx.x >> 6);
  bf16x8 v = *(const bf16x8*)(hsrc + row * 512 + lane * 8);
  float s = 0.f, s2 = 0.f;
  #pragma unroll
  for (int j = 0; j < 8; ++j) { float f = bf2f((uint16_t)v[j]); s += f; s2 += f * f; }
  #pragma unroll
  for (int o = 1; o < 64; o <<= 1) { s += __shfl_xor(s, o); s2 += __shfl_xor(s2, o); }
  if (lane == 0) {
    float mu  = s * (1.f / 512.f);
    float var = s2 * (1.f / 512.f) - mu * mu;
    float rs  = rsqrtf(var + 1e-5f);
    rstd_a[row] = rs;
    murs_a[row] = mu * rs;
  }
}

// ---------------------------------------------------------------------------
// u[n] = sum_k ln_b[k]*W1[n,k] + b1[n] ;  v[n] = sum_k ln_g[k]*W1[n,k]
// ---------------------------------------------------------------------------
__global__ void uv_kernel(const float* __restrict__ W1, const float* __restrict__ ln_g,
                          const float* __restrict__ ln_b, const float* __restrict__ b1,
                          float* __restrict__ u, float* __restrict__ v)
{
  const int lane = threadIdx.x & 63;
  const int row  = blockIdx.x * 4 + (threadIdx.x >> 6);
  const float* wp = W1 + (size_t)row * 512 + lane * 8;
  float4 w0 = *(const float4*)wp;
  float4 w1 = *(const float4*)(wp + 4);
  float4 g0 = *(const float4*)(ln_g + lane * 8);
  float4 g1 = *(const float4*)(ln_g + lane * 8 + 4);
  float4 b0 = *(const float4*)(ln_b + lane * 8);
  float4 b1v = *(const float4*)(ln_b + lane * 8 + 4);
  float su = b0.x * w0.x + b0.y * w0.y + b0.z * w0.z + b0.w * w0.w
           + b1v.x * w1.x + b1v.y * w1.y + b1v.z * w1.z + b1v.w * w1.w;
  float sv = g0.x * w0.x + g0.y * w0.y + g0.z * w0.z + g0.w * w0.w
           + g1.x * w1.x + g1.y * w1.y + g1.z * w1.z + g1.w * w1.w;
  #pragma unroll
  for (int o = 1; o < 64; o <<= 1) { su += __shfl_xor(su, o); sv += __shfl_xor(sv, o); }
  if (lane == 0) { u[row] = su + b1[row]; v[row] = sv; }
}

// ---------------------------------------------------------------------------
// Fused GEMM: C = tanh(epilogue(A[64 rows, K=512] @ W[,512]^T))
// A staged full-K in LDS once (64KB, swizzled) -> in-place C writes are safe.
// MODE 0: LN-affine epilogue  tanh(rstd_m*G - murs_m*v_n + u_n)   (u has +b1)
// MODE 1: bias epilogue       tanh(G + bias_n)
// ---------------------------------------------------------------------------
template<int MODE>
__global__ __launch_bounds__(256, 2) void gemm_fused(
    const uint16_t* __restrict__ Abase, const uint16_t* __restrict__ W,
    uint16_t* __restrict__ C, int ntiles,
    const float* __restrict__ rstd_a, const float* __restrict__ murs_a,
    const float* __restrict__ uvec, const float* __restrict__ vvec,
    const float* __restrict__ bias)
{
  __shared__ uint16_t At[64 * 512];   // 65536 B
  const int tid  = threadIdx.x;
  const int lane = tid & 63;
  const int wv   = tid >> 6;
  const size_t mbase = (size_t)blockIdx.x * 64;

  // stage 64 rows x full K, pre-swizzled source -> linear LDS dest
  for (int r8 = 0; r8 < 16; ++r8) {
    int row = wv * 16 + r8;
    int sb  = (lane * 16) ^ ((row & 7) << 4);       // byte pos in 1024B row
    gll16(Abase + (mbase + row) * 512 + sb / 2, At + row * 512);
  }
  __syncthreads();

  const int fr = lane & 15, kg = lane >> 4;
  const int mloc = (wv & 1) * 32;
  const int nhalf = (wv >> 1) * 64;

  for (int nt = 0; nt < ntiles; ++nt) {
    const int nbase = nt * 128 + nhalf;
    f32x4 vz = {0.f, 0.f, 0.f, 0.f};
    f32x4 acc[4][2];
    #pragma unroll
    for (int i = 0; i < 4; ++i) { acc[i][0] = vz; acc[i][1] = vz; }

    #pragma unroll 4
    for (int kb = 0; kb < 16; ++kb) {
      const int ke = kb * 32 + kg * 8;              // element offset in K
      bf16x8 wf[4];
      #pragma unroll
      for (int i = 0; i < 4; ++i)
        wf[i] = *(const bf16x8*)(W + (size_t)(nbase + i * 16 + fr) * 512 + ke);
      bf16x8 af[2];
      #pragma unroll
      for (int j = 0; j < 2; ++j) {
        int mr = mloc + j * 16 + fr;
        af[j] = *(const bf16x8*)((const char*)At + ((mr * 1024 + ke * 2) ^ ((mr & 7) << 4)));
      }
      #pragma unroll
      for (int i = 0; i < 4; ++i)
        #pragma unroll
        for (int j = 0; j < 2; ++j)
          acc[i][j] = __builtin_amdgcn_mfma_f32_16x16x32_bf16(wf[i], af[j], acc[i][j], 0, 0, 0);
    }

    #pragma unroll
    for (int j = 0; j < 2; ++j) {
      size_t m = mbase + mloc + j * 16 + fr;
      float rs = 0.f, mrs = 0.f;
      if constexpr (MODE == 0) { rs = rstd_a[m]; mrs = murs_a[m]; }
      #pragma unroll
      for (int i = 0; i < 4; ++i) {
        int n = nbase + i * 16 + kg * 4;
        float o0, o1, o2, o3;
        if constexpr (MODE == 0) {
          float4 uu = *(const float4*)(uvec + n);
          float4 vv = *(const float4*)(vvec + n);
          o0 = tanh_fast(rs * acc[i][j][0] - mrs * vv.x + uu.x);
          o1 = tanh_fast(rs * acc[i][j][1] - mrs * vv.y + uu.y);
          o2 = tanh_fast(rs * acc[i][j][2] - mrs * vv.z + uu.z);
          o3 = tanh_fast(rs * acc[i][j][3] - mrs * vv.w + uu.w);
        } else {
          float4 bb = *(const float4*)(bias + n);
          o0 = tanh_fast(acc[i][j][0] + bb.x);
          o1 = tanh_fast(acc[i][j][1] + bb.y);
          o2 = tanh_fast(acc[i][j][2] + bb.z);
          o3 = tanh_fast(acc[i][j][3] + bb.w);
        }
        uint32_t lo = (uint32_t)f2bf(o0) | ((uint32_t)f2bf(o1) << 16);
        uint32_t hi = (uint32_t)f2bf(o2) | ((uint32_t)f2bf(o3) << 16);
        *(uint64_t*)(C + m * 512 + n) = (uint64_t)lo | ((uint64_t)hi << 32);
      }
    }
    __syncthreads();  // keep waves together before next n-tile reads At
  }
}

// ---------------------------------------------------------------------------
// value[m] = a2[m,:256] . Wv + bv   (a2 at stride 512; one wave per row)
// ---------------------------------------------------------------------------
__global__ void gemv_kernel(const uint16_t* __restrict__ a2, const float* __restrict__ Wv,
                            const float* __restrict__ bv, float* __restrict__ outv)
{
  const int lane = threadIdx.x & 63;
  const size_t row = (size_t)blockIdx.x * 4 + (threadIdx.x >> 6);
  const uint16_t* p = a2 + row * 512 + lane * 4;
  uint64_t v = *(const uint64_t*)p;
  float4 w = *(const float4*)(Wv + lane * 4);
  float d = bf2f((uint16_t)(v & 0xFFFF)) * w.x
          + bf2f((uint16_t)((v >> 16) & 0xFFFF)) * w.y
          + bf2f((uint16_t)((v >> 32) & 0xFFFF)) * w.z
          + bf2f((uint16_t)((v >> 48) & 0xFFFF)) * w.w;
  #pragma unroll
  for (int o = 1; o < 64; o <<= 1) d += __shfl_xor(d, o);
  if (lane == 0) outv[row] = d + bv[0];
}

// ---------------------------------------------------------------------------
// W1 (fold ln_g into columns) then W2, fp32 -> bf16 contiguous.
// ---------------------------------------------------------------------------
__global__ void wconv_kernel(const float* __restrict__ W1, const float* __restrict__ W2,
                             const float* __restrict__ ln_g, uint16_t* __restrict__ dst)
{
  int idx = blockIdx.x * 256 + threadIdx.x;
  int i4 = idx * 4;
  float4 v;
  if (i4 < 262144) {
    v = *(const float4*)(W1 + i4);
    int c = i4 & 511;
    float4 gv = *(const float4*)(ln_g + c);
    v.x *= gv.x; v.y *= gv.y; v.z *= gv.z; v.w *= gv.w;
  } else {
    v = *(const float4*)(W2 + (i4 - 262144));
  }
  uint32_t lo = (uint32_t)f2bf(v.x) | ((uint32_t)f2bf(v.y) << 16);
  uint32_t hi = (uint32_t)f2bf(v.z) | ((uint32_t)f2bf(v.w) << 16);
  *(uint64_t*)(dst + i4) = (uint64_t)lo | ((uint64_t)hi << 32);
}

extern "C" void kernel_launch(void* const* d_in, const int* in_sizes, int n_in,
                              void* d_out, int out_size, void* d_ws, size_t ws_size,
                              hipStream_t stream)
{
  (void)in_sizes; (void)n_in;
  const float* x    = (const float*)d_in[0];
  const float* done = (const float*)d_in[1];
  const float* h0   = (const float*)d_in[2];
  const float* c0   = (const float*)d_in[3];
  const float* W_ih = (const float*)d_in[4];
  const float* W_hh = (const float*)d_in[5];
  const float* b_ih = (const float*)d_in[6];
  const float* b_hh = (const float*)d_in[7];
  const float* ln_g = (const float*)d_in[8];
  const float* ln_b = (const float*)d_in[9];
  const float* W1   = (const float*)d_in[10];
  const float* b1   = (const float*)d_in[11];
  const float* W2   = (const float*)d_in[12];
  const float* b2   = (const float*)d_in[13];
  const float* Wv   = (const float*)d_in[14];
  const float* bv   = (const float*)d_in[15];
  float* out = (float*)d_out;
  char* ws = (char*)d_ws;

  // ws layout (bytes):
  //   0        flg      16384    (8 groups x 32 WG flags, 128B/group block)
  //   16384    wbf      786432   (bf16 W1g | W2)
  //   802816   u,v      4096     (512 f32 each)
  //   806912   rstd     524288
  //   1331200  murs     524288
  //   2097152  hs       134217728  (bf16 [T*B,512]; later a1 in-place, a2 cols 0..255)
  constexpr size_t NEED = 2097152ULL + 134217728ULL;
  if (ws_size < NEED) {
    hipMemsetAsync(d_out, 0, (size_t)out_size * 4, stream);
    return;
  }
  uint32_t* flg  = (uint32_t*)ws;
  uint16_t* wbf  = (uint16_t*)(ws + 16384);
  float*    uv_u = (float*)(ws + 802816);
  float*    uv_v = (float*)(ws + 802816 + 2048);
  float*    rstd = (float*)(ws + 806912);
  float*    murs = (float*)(ws + 1331200);
  uint16_t* hsb  = (uint16_t*)(ws + 2097152);

  hipMemsetAsync(flg, 0, 16384, stream);
  hipLaunchKernelGGL(wconv_kernel, dim3(384), dim3(256), 0, stream, W1, W2, ln_g, wbf);
  hipLaunchKernelGGL(uv_kernel, dim3(128), dim3(256), 0, stream, W1, ln_g, ln_b, b1, uv_u, uv_v);
  hipLaunchKernelGGL(lstm_kernel, dim3(256), dim3(256), 0, stream,
                     x, done, h0, c0, W_ih, W_hh, b_ih, b_hh, hsb, flg, out);
  hipLaunchKernelGGL(ln_stats_kernel, dim3(32768), dim3(256), 0, stream, hsb, rstd, murs);
  // GEMM1: a1 = tanh(LN(h) @ W1^T + b1), in-place over hs
  hipLaunchKernelGGL((gemm_fused<0>), dim3(2048), dim3(256), 0, stream,
                     hsb, wbf, hsb, 4, rstd, murs, uv_u, uv_v, (const float*)nullptr);
  // GEMM2: a2 = tanh(a1 @ W2^T + b2), in-place over hs cols [0,256)
  hipLaunchKernelGGL((gemm_fused<1>), dim3(2048), dim3(256), 0, stream,
                     hsb, wbf + 262144, hsb, 2,
                     (const float*)nullptr, (const float*)nullptr,
                     (const float*)nullptr, (const float*)nullptr, b2);
  hipLaunchKernelGGL(gemv_kernel, dim3(32768), dim3(256), 0, stream, hsb, Wv, bv, out);
}

// Round 5
// 2866.197 us; speedup vs baseline: 2.6159x; 2.6159x over previous
//
#include <hip/hip_runtime.h>
#include <stdint.h>

// Problem constants
constexpr int T_STEPS = 512;
constexpr int BSZ     = 256;
constexpr int OBSD    = 64;
constexpr int HID     = 512;
constexpr int NROWS   = T_STEPS * BSZ;   // 131072

// LSTM partitioning: 8 groups x 32 WGs; group owns 32 batch rows; WG owns 16 h-cols
constexpr int GROUPS = 8;
constexpr int WPG    = 32;
constexpr int BW     = 32;

typedef __attribute__((ext_vector_type(8))) short bf16x8;
typedef __attribute__((ext_vector_type(4))) float f32x4;

__device__ __forceinline__ float bf2f(uint16_t u) {
  union { uint32_t i; float f; } v; v.i = ((uint32_t)u) << 16; return v.f;
}
__device__ __forceinline__ uint16_t f2bf(float f) {
  union { float f; uint32_t i; } v; v.f = f;
  return (uint16_t)((v.i + 0x7FFFu + ((v.i >> 16) & 1u)) >> 16);
}
__device__ __forceinline__ uint64_t pack4(float a, float b, float c, float d) {
  uint32_t lo = (uint32_t)f2bf(a) | ((uint32_t)f2bf(b) << 16);
  uint32_t hi = (uint32_t)f2bf(c) | ((uint32_t)f2bf(d) << 16);
  return (uint64_t)lo | ((uint64_t)hi << 32);
}
__device__ __forceinline__ float sigm(float x) { return 1.f / (1.f + __expf(-x)); }
__device__ __forceinline__ float tanh_fast(float x) {
  float e = __expf(2.f * x);
  return 1.f - 2.f / (e + 1.f);
}

__device__ __forceinline__ void gll16(const void* g, void* l) {
  __builtin_amdgcn_global_load_lds(
      (const __attribute__((address_space(1))) uint32_t*)g,
      (__attribute__((address_space(3))) uint32_t*)l, 16, 0, 0);
}

// ---------------------------------------------------------------------------
// Persistent LSTM scan kernel. 256 blocks x 256 threads, 1 block/CU.
// Sync protocol (no cache-invalidating fences):
//   producer: sc1 h-stores -> __syncthreads (per-wave vmcnt(0) drain) ->
//             RELAXED agent flag store (LIC serializes flag-after-data).
//   consumer: RELAXED agent flag poll (s_sleep(1) backoff) ->
//             workgroup-scope acquire fence (compiler ordering, NO buffer_inv)
//             -> sc1 h-loads (cache-bypassing, so no invalidate needed).
// x/done/weights stay L2-resident all 512 steps (nothing invalidates L2).
// Weights in VGPRs (18 x bf16x8/wave). h-gather coalesced (512B per instr).
// LDS: Ab 36864 B | gl 8704 B (pad 17) | bl 256 B  = 45824 B (static)
// ---------------------------------------------------------------------------
__global__ __launch_bounds__(256, 1) void lstm_kernel(
    const float* __restrict__ xin, const float* __restrict__ done,
    const float* __restrict__ h0, const float* __restrict__ c0,
    const float* __restrict__ W_ih, const float* __restrict__ W_hh,
    const float* __restrict__ b_ih, const float* __restrict__ b_hh,
    uint16_t* __restrict__ hs, uint32_t* __restrict__ flg,
    float* __restrict__ out)
{
  __shared__ char  Ab[32 * 1152];
  __shared__ float gl[4 * 544];     // [gate][32 rows][17 pad]
  __shared__ float bl[64];

  const int wg   = blockIdx.x;
  const int g    = wg / WPG;
  const int win  = wg % WPG;
  const int bg   = g * BW;
  const int tid  = threadIdx.x;
  const int lane = tid & 63;
  const int q    = tid >> 6;   // wave id == gate id (i,f,g,o)

  // ---- one-time: this wave's weight fragments straight into VGPRs ----
  bf16x8 bq[18];
  {
    const int wrow = q * 512 + win * 16 + (lane & 15);
    const int kg8  = (lane >> 4) * 8;
    #pragma unroll
    for (int ks = 0; ks < 18; ++ks) {
      const float* src = (ks < 16)
          ? (W_hh + (size_t)wrow * 512 + ks * 32 + kg8)
          : (W_ih + (size_t)wrow * 64 + (ks - 16) * 32 + kg8);
      float4 a = *(const float4*)src;
      float4 b = *(const float4*)(src + 4);
      bf16x8 v;
      v[0] = (short)f2bf(a.x); v[1] = (short)f2bf(a.y);
      v[2] = (short)f2bf(a.z); v[3] = (short)f2bf(a.w);
      v[4] = (short)f2bf(b.x); v[5] = (short)f2bf(b.y);
      v[6] = (short)f2bf(b.z); v[7] = (short)f2bf(b.w);
      bq[ks] = v;
    }
  }
  if (tid < 64) {
    int q2 = tid >> 4, c = tid & 15;
    int grow = q2 * 512 + win * 16 + c;
    bl[tid] = b_ih[grow] + b_hh[grow];
  }

  const int b_loc = tid >> 3;        // 0..31 (batch row within group)
  const int n0    = (tid & 7) * 2;   // h-col pair within WG's 16 cols
  float creg0 = c0[(size_t)(bg + b_loc) * HID + win * 16 + n0];
  float creg1 = c0[(size_t)(bg + b_loc) * HID + win * 16 + n0 + 1];

  const int sr  = tid >> 3;          // x staging row
  const int sc8 = (tid & 7) * 8;     // x col base
  const int rw  = q * 8;             // wave's first h row

  __syncthreads();

  for (int t = 0; t < T_STEPS; ++t) {
    // ---- hoisted loads (overlap the poll): x_t, done values ----
    const float* xp = xin + ((size_t)t * BSZ + bg + sr) * OBSD + sc8;
    float4 xa = *(const float4*)xp;
    float4 xb = *(const float4*)(xp + 4);
    float dvs[8];
    #pragma unroll
    for (int r8 = 0; r8 < 8; ++r8)
      dvs[r8] = done[(size_t)t * BSZ + bg + rw + r8];
    float dv_b = done[(size_t)t * BSZ + bg + b_loc];

    // stage x_t into Ab (two barriers since prev MFMA read -> no race)
    {
      uint4 u4;
      u4.x = (uint32_t)f2bf(xa.x) | ((uint32_t)f2bf(xa.y) << 16);
      u4.y = (uint32_t)f2bf(xa.z) | ((uint32_t)f2bf(xa.w) << 16);
      u4.z = (uint32_t)f2bf(xb.x) | ((uint32_t)f2bf(xb.y) << 16);
      u4.w = (uint32_t)f2bf(xb.z) | ((uint32_t)f2bf(xb.w) << 16);
      *(uint4*)(Ab + ((sr * 1152 + 1024 + sc8 * 2) ^ ((sr & 7) << 4))) = u4;
    }

    // ---- wait for the whole group's step t-1 flags (every wave polls) ----
    if (t > 0) {
      for (;;) {
        uint32_t f = (lane < WPG)
            ? __hip_atomic_load(flg + g * 32 + lane, __ATOMIC_RELAXED, __HIP_MEMORY_SCOPE_AGENT)
            : 0xFFFFFFFFu;
        if (__all((int)(f >= (uint32_t)t))) break;
        __builtin_amdgcn_s_sleep(1);
      }
      // ordering only -- no cache invalidation (h loads below are sc1 anyway)
      __builtin_amdgcn_fence(__ATOMIC_ACQUIRE, "workgroup");
    }

    // ---- stage h_{t-1}: wave loads its 8 rows, coalesced 512B per instr ----
    if (t == 0) {
      #pragma unroll
      for (int r8 = 0; r8 < 8; ++r8) {
        int r = rw + r8;
        uint64_t v0 = 0, v1 = 0;
        if (dvs[r8] <= 0.5f) {
          const float* hp = h0 + (size_t)(bg + r) * HID;
          float4 ha = *(const float4*)(hp + lane * 4);
          float4 hb = *(const float4*)(hp + 256 + lane * 4);
          v0 = pack4(ha.x, ha.y, ha.z, ha.w);
          v1 = pack4(hb.x, hb.y, hb.z, hb.w);
        }
        *(uint64_t*)(Ab + ((r * 1152 + lane * 8) ^ ((r & 7) << 4))) = v0;
        *(uint64_t*)(Ab + ((r * 1152 + 512 + lane * 8) ^ ((r & 7) << 4))) = v1;
      }
    } else {
      #pragma unroll
      for (int r8 = 0; r8 < 8; ++r8) {
        int r = rw + r8;
        const uint64_t* hrow =
            (const uint64_t*)hs + ((size_t)(t - 1) * BSZ + bg + r) * 128;
        uint64_t v0 = __hip_atomic_load(hrow + lane, __ATOMIC_RELAXED, __HIP_MEMORY_SCOPE_AGENT);
        uint64_t v1 = __hip_atomic_load(hrow + 64 + lane, __ATOMIC_RELAXED, __HIP_MEMORY_SCOPE_AGENT);
        if (dvs[r8] > 0.5f) { v0 = 0; v1 = 0; }
        *(uint64_t*)(Ab + ((r * 1152 + lane * 8) ^ ((r & 7) << 4))) = v0;
        *(uint64_t*)(Ab + ((r * 1152 + 512 + lane * 8) ^ ((r & 7) << 4))) = v1;
      }
    }
    __syncthreads();

    // ---- MFMA: gates[32 batch, 16 cols] for wave's gate q (B from VGPRs) ----
    f32x4 ac0 = {0.f, 0.f, 0.f, 0.f};
    f32x4 ac1 = {0.f, 0.f, 0.f, 0.f};
    {
      const int ar = lane & 15;
      const int kg = lane >> 4;
      #pragma unroll
      for (int ks = 0; ks < 18; ++ks) {
        int kb = (ks * 32 + kg * 8) * 2;
        bf16x8 a0 = *(const bf16x8*)(Ab + ((ar * 1152 + kb) ^ ((ar & 7) << 4)));
        bf16x8 a1 = *(const bf16x8*)(Ab + (((ar + 16) * 1152 + kb) ^ ((ar & 7) << 4)));
        ac0 = __builtin_amdgcn_mfma_f32_16x16x32_bf16(a0, bq[ks], ac0, 0, 0, 0);
        ac1 = __builtin_amdgcn_mfma_f32_16x16x32_bf16(a1, bq[ks], ac1, 0, 0, 0);
      }
    }
    // ---- gates -> LDS exchange (rows padded to 17 words) ----
    {
      int c  = lane & 15;
      int rb = (lane >> 4) * 4;
      #pragma unroll
      for (int r = 0; r < 4; ++r) {
        gl[q * 544 + (rb + r) * 17 + c]      = ac0[r];
        gl[q * 544 + (16 + rb + r) * 17 + c] = ac1[r];
      }
    }
    __syncthreads();
    // ---- cell update (c lives in registers across all 512 steps) ----
    {
      float m = dv_b > 0.5f ? 0.f : 1.f;
      float h0v, h1v;
      {
        float I = gl[b_loc * 17 + n0]         + bl[n0];
        float F = gl[544 + b_loc * 17 + n0]   + bl[16 + n0];
        float G = gl[1088 + b_loc * 17 + n0]  + bl[32 + n0];
        float O = gl[1632 + b_loc * 17 + n0]  + bl[48 + n0];
        float cc = creg0 * m;
        cc = sigm(F) * cc + sigm(I) * tanh_fast(G);
        creg0 = cc;
        h0v = sigm(O) * tanh_fast(cc);
      }
      {
        int n1 = n0 + 1;
        float I = gl[b_loc * 17 + n1]         + bl[n1];
        float F = gl[544 + b_loc * 17 + n1]   + bl[16 + n1];
        float G = gl[1088 + b_loc * 17 + n1]  + bl[32 + n1];
        float O = gl[1632 + b_loc * 17 + n1]  + bl[48 + n1];
        float cc = creg1 * m;
        cc = sigm(F) * cc + sigm(I) * tanh_fast(G);
        creg1 = cc;
        h1v = sigm(O) * tanh_fast(cc);
      }
      uint32_t pk = (uint32_t)f2bf(h0v) | ((uint32_t)f2bf(h1v) << 16);
      uint32_t* hp = (uint32_t*)(hs + ((size_t)t * BSZ + bg + b_loc) * HID + win * 16 + n0);
      __hip_atomic_store(hp, pk, __ATOMIC_RELAXED, __HIP_MEMORY_SCOPE_AGENT);
      if (t == T_STEPS - 1) {
        size_t ob = (size_t)(bg + b_loc) * HID + win * 16 + n0;
        out[NROWS + ob]         = h0v;
        out[NROWS + ob + 1]     = h1v;
        out[2 * NROWS + ob]     = creg0;
        out[2 * NROWS + ob + 1] = creg1;
      }
    }
    __syncthreads();   // per-wave vmcnt(0) drain -> all h sc1 stores ACKed at LIC
    if (tid == 0)      // LIC serializes flag-after-data; no release fence needed
      __hip_atomic_store(flg + g * 32 + win, (uint32_t)(t + 1),
                         __ATOMIC_RELAXED, __HIP_MEMORY_SCOPE_AGENT);
  }
}

// ---------------------------------------------------------------------------
// Per-row LayerNorm stats from bf16 hidden: rstd[m], murs[m] = mu*rstd.
// ---------------------------------------------------------------------------
__global__ void ln_stats_kernel(const uint16_t* __restrict__ hsrc,
                                float* __restrict__ rstd_a, float* __restrict__ murs_a)
{
  const int lane = threadIdx.x & 63;
  const size_t row = (size_t)blockIdx.x * 4 + (threadIdx.x >> 6);
  bf16x8 v = *(const bf16x8*)(hsrc + row * 512 + lane * 8);
  float s = 0.f, s2 = 0.f;
  #pragma unroll
  for (int j = 0; j < 8; ++j) { float f = bf2f((uint16_t)v[j]); s += f; s2 += f * f; }
  #pragma unroll
  for (int o = 1; o < 64; o <<= 1) { s += __shfl_xor(s, o); s2 += __shfl_xor(s2, o); }
  if (lane == 0) {
    float mu  = s * (1.f / 512.f);
    float var = s2 * (1.f / 512.f) - mu * mu;
    float rs  = rsqrtf(var + 1e-5f);
    rstd_a[row] = rs;
    murs_a[row] = mu * rs;
  }
}

// ---------------------------------------------------------------------------
// u[n] = sum_k ln_b[k]*W1[n,k] + b1[n] ;  v[n] = sum_k ln_g[k]*W1[n,k]
// ---------------------------------------------------------------------------
__global__ void uv_kernel(const float* __restrict__ W1, const float* __restrict__ ln_g,
                          const float* __restrict__ ln_b, const float* __restrict__ b1,
                          float* __restrict__ u, float* __restrict__ v)
{
  const int lane = threadIdx.x & 63;
  const int row  = blockIdx.x * 4 + (threadIdx.x >> 6);
  const float* wp = W1 + (size_t)row * 512 + lane * 8;
  float4 w0 = *(const float4*)wp;
  float4 w1 = *(const float4*)(wp + 4);
  float4 g0 = *(const float4*)(ln_g + lane * 8);
  float4 g1 = *(const float4*)(ln_g + lane * 8 + 4);
  float4 b0 = *(const float4*)(ln_b + lane * 8);
  float4 b1v = *(const float4*)(ln_b + lane * 8 + 4);
  float su = b0.x * w0.x + b0.y * w0.y + b0.z * w0.z + b0.w * w0.w
           + b1v.x * w1.x + b1v.y * w1.y + b1v.z * w1.z + b1v.w * w1.w;
  float sv = g0.x * w0.x + g0.y * w0.y + g0.z * w0.z + g0.w * w0.w
           + g1.x * w1.x + g1.y * w1.y + g1.z * w1.z + g1.w * w1.w;
  #pragma unroll
  for (int o = 1; o < 64; o <<= 1) { su += __shfl_xor(su, o); sv += __shfl_xor(sv, o); }
  if (lane == 0) { u[row] = su + b1[row]; v[row] = sv; }
}

// ---------------------------------------------------------------------------
// Fused GEMM: C = tanh(epilogue(A[64 rows, K=512] @ W[,512]^T))
// MODE 0: LN-affine epilogue  tanh(rstd_m*G - murs_m*v_n + u_n)   (u has +b1)
// MODE 1: bias epilogue       tanh(G + bias_n)
// ---------------------------------------------------------------------------
template<int MODE>
__global__ __launch_bounds__(256, 2) void gemm_fused(
    const uint16_t* __restrict__ Abase, const uint16_t* __restrict__ W,
    uint16_t* __restrict__ C, int ntiles,
    const float* __restrict__ rstd_a, const float* __restrict__ murs_a,
    const float* __restrict__ uvec, const float* __restrict__ vvec,
    const float* __restrict__ bias)
{
  __shared__ uint16_t At[64 * 512];   // 65536 B
  const int tid  = threadIdx.x;
  const int lane = tid & 63;
  const int wv   = tid >> 6;
  const size_t mbase = (size_t)blockIdx.x * 64;

  for (int r8 = 0; r8 < 16; ++r8) {
    int row = wv * 16 + r8;
    int sb  = (lane * 16) ^ ((row & 7) << 4);
    gll16(Abase + (mbase + row) * 512 + sb / 2, At + row * 512);
  }
  __syncthreads();

  const int fr = lane & 15, kg = lane >> 4;
  const int mloc = (wv & 1) * 32;
  const int nhalf = (wv >> 1) * 64;

  for (int nt = 0; nt < ntiles; ++nt) {
    const int nbase = nt * 128 + nhalf;
    f32x4 vz = {0.f, 0.f, 0.f, 0.f};
    f32x4 acc[4][2];
    #pragma unroll
    for (int i = 0; i < 4; ++i) { acc[i][0] = vz; acc[i][1] = vz; }

    #pragma unroll 4
    for (int kb = 0; kb < 16; ++kb) {
      const int ke = kb * 32 + kg * 8;
      bf16x8 wf[4];
      #pragma unroll
      for (int i = 0; i < 4; ++i)
        wf[i] = *(const bf16x8*)(W + (size_t)(nbase + i * 16 + fr) * 512 + ke);
      bf16x8 af[2];
      #pragma unroll
      for (int j = 0; j < 2; ++j) {
        int mr = mloc + j * 16 + fr;
        af[j] = *(const bf16x8*)((const char*)At + ((mr * 1024 + ke * 2) ^ ((mr & 7) << 4)));
      }
      #pragma unroll
      for (int i = 0; i < 4; ++i)
        #pragma unroll
        for (int j = 0; j < 2; ++j)
          acc[i][j] = __builtin_amdgcn_mfma_f32_16x16x32_bf16(wf[i], af[j], acc[i][j], 0, 0, 0);
    }

    #pragma unroll
    for (int j = 0; j < 2; ++j) {
      size_t m = mbase + mloc + j * 16 + fr;
      float rs = 0.f, mrs = 0.f;
      if constexpr (MODE == 0) { rs = rstd_a[m]; mrs = murs_a[m]; }
      #pragma unroll
      for (int i = 0; i < 4; ++i) {
        int n = nbase + i * 16 + kg * 4;
        float o0, o1, o2, o3;
        if constexpr (MODE == 0) {
          float4 uu = *(const float4*)(uvec + n);
          float4 vv = *(const float4*)(vvec + n);
          o0 = tanh_fast(rs * acc[i][j][0] - mrs * vv.x + uu.x);
          o1 = tanh_fast(rs * acc[i][j][1] - mrs * vv.y + uu.y);
          o2 = tanh_fast(rs * acc[i][j][2] - mrs * vv.z + uu.z);
          o3 = tanh_fast(rs * acc[i][j][3] - mrs * vv.w + uu.w);
        } else {
          float4 bb = *(const float4*)(bias + n);
          o0 = tanh_fast(acc[i][j][0] + bb.x);
          o1 = tanh_fast(acc[i][j][1] + bb.y);
          o2 = tanh_fast(acc[i][j][2] + bb.z);
          o3 = tanh_fast(acc[i][j][3] + bb.w);
        }
        uint32_t lo = (uint32_t)f2bf(o0) | ((uint32_t)f2bf(o1) << 16);
        uint32_t hi = (uint32_t)f2bf(o2) | ((uint32_t)f2bf(o3) << 16);
        *(uint64_t*)(C + m * 512 + n) = (uint64_t)lo | ((uint64_t)hi << 32);
      }
    }
    __syncthreads();
  }
}

// ---------------------------------------------------------------------------
// value[m] = a2[m,:256] . Wv + bv   (a2 at stride 512; one wave per row)
// ---------------------------------------------------------------------------
__global__ void gemv_kernel(const uint16_t* __restrict__ a2, const float* __restrict__ Wv,
                            const float* __restrict__ bv, float* __restrict__ outv)
{
  const int lane = threadIdx.x & 63;
  const size_t row = (size_t)blockIdx.x * 4 + (threadIdx.x >> 6);
  const uint16_t* p = a2 + row * 512 + lane * 4;
  uint64_t v = *(const uint64_t*)p;
  float4 w = *(const float4*)(Wv + lane * 4);
  float d = bf2f((uint16_t)(v & 0xFFFF)) * w.x
          + bf2f((uint16_t)((v >> 16) & 0xFFFF)) * w.y
          + bf2f((uint16_t)((v >> 32) & 0xFFFF)) * w.z
          + bf2f((uint16_t)((v >> 48) & 0xFFFF)) * w.w;
  #pragma unroll
  for (int o = 1; o < 64; o <<= 1) d += __shfl_xor(d, o);
  if (lane == 0) outv[row] = d + bv[0];
}

// ---------------------------------------------------------------------------
// W1 (fold ln_g into columns) then W2, fp32 -> bf16 contiguous.
// ---------------------------------------------------------------------------
__global__ void wconv_kernel(const float* __restrict__ W1, const float* __restrict__ W2,
                             const float* __restrict__ ln_g, uint16_t* __restrict__ dst)
{
  int idx = blockIdx.x * 256 + threadIdx.x;
  int i4 = idx * 4;
  float4 v;
  if (i4 < 262144) {
    v = *(const float4*)(W1 + i4);
    int c = i4 & 511;
    float4 gv = *(const float4*)(ln_g + c);
    v.x *= gv.x; v.y *= gv.y; v.z *= gv.z; v.w *= gv.w;
  } else {
    v = *(const float4*)(W2 + (i4 - 262144));
  }
  uint32_t lo = (uint32_t)f2bf(v.x) | ((uint32_t)f2bf(v.y) << 16);
  uint32_t hi = (uint32_t)f2bf(v.z) | ((uint32_t)f2bf(v.w) << 16);
  *(uint64_t*)(dst + i4) = (uint64_t)lo | ((uint64_t)hi << 32);
}

extern "C" void kernel_launch(void* const* d_in, const int* in_sizes, int n_in,
                              void* d_out, int out_size, void* d_ws, size_t ws_size,
                              hipStream_t stream)
{
  (void)in_sizes; (void)n_in;
  const float* x    = (const float*)d_in[0];
  const float* done = (const float*)d_in[1];
  const float* h0   = (const float*)d_in[2];
  const float* c0   = (const float*)d_in[3];
  const float* W_ih = (const float*)d_in[4];
  const float* W_hh = (const float*)d_in[5];
  const float* b_ih = (const float*)d_in[6];
  const float* b_hh = (const float*)d_in[7];
  const float* ln_g = (const float*)d_in[8];
  const float* ln_b = (const float*)d_in[9];
  const float* W1   = (const float*)d_in[10];
  const float* b1   = (const float*)d_in[11];
  const float* W2   = (const float*)d_in[12];
  const float* b2   = (const float*)d_in[13];
  const float* Wv   = (const float*)d_in[14];
  const float* bv   = (const float*)d_in[15];
  float* out = (float*)d_out;
  char* ws = (char*)d_ws;

  // ws layout (bytes):
  //   0        flg      16384    (8 groups x 32 WG flags, 128B/group block)
  //   16384    wbf      786432   (bf16 W1g | W2)
  //   802816   u,v      4096     (512 f32 each)
  //   806912   rstd     524288
  //   1331200  murs     524288
  //   2097152  hs       134217728  (bf16 [T*B,512]; later a1 in-place, a2 cols 0..255)
  constexpr size_t NEED = 2097152ULL + 134217728ULL;
  if (ws_size < NEED) {
    hipMemsetAsync(d_out, 0, (size_t)out_size * 4, stream);
    return;
  }
  uint32_t* flg  = (uint32_t*)ws;
  uint16_t* wbf  = (uint16_t*)(ws + 16384);
  float*    uv_u = (float*)(ws + 802816);
  float*    uv_v = (float*)(ws + 802816 + 2048);
  float*    rstd = (float*)(ws + 806912);
  float*    murs = (float*)(ws + 1331200);
  uint16_t* hsb  = (uint16_t*)(ws + 2097152);

  hipMemsetAsync(flg, 0, 16384, stream);
  hipLaunchKernelGGL(wconv_kernel, dim3(384), dim3(256), 0, stream, W1, W2, ln_g, wbf);
  hipLaunchKernelGGL(uv_kernel, dim3(128), dim3(256), 0, stream, W1, ln_g, ln_b, b1, uv_u, uv_v);
  hipLaunchKernelGGL(lstm_kernel, dim3(256), dim3(256), 0, stream,
                     x, done, h0, c0, W_ih, W_hh, b_ih, b_hh, hsb, flg, out);
  hipLaunchKernelGGL(ln_stats_kernel, dim3(32768), dim3(256), 0, stream, hsb, rstd, murs);
  // GEMM1: a1 = tanh(LN(h) @ W1^T + b1), in-place over hs
  hipLaunchKernelGGL((gemm_fused<0>), dim3(2048), dim3(256), 0, stream,
                     hsb, wbf, hsb, 4, rstd, murs, uv_u, uv_v, (const float*)nullptr);
  // GEMM2: a2 = tanh(a1 @ W2^T + b2), in-place over hs cols [0,256)
  hipLaunchKernelGGL((gemm_fused<1>), dim3(2048), dim3(256), 0, stream,
                     hsb, wbf + 262144, hsb, 2,
                     (const float*)nullptr, (const float*)nullptr,
                     (const float*)nullptr, (const float*)nullptr, b2);
  hipLaunchKernelGGL(gemv_kernel, dim3(32768), dim3(256), 0, stream, hsb, Wv, bv, out);
}